// Round 6
// baseline (615.561 us; speedup 1.0000x reference)
//
#include <hip/hip_runtime.h>
#include <hip/hip_bf16.h>

#define BN     6
#define NQ     10000
#define DIM    256
#define HEADS  8
#define HDD    32
#define HF_    32
#define WF_    88
#define HW_    (HF_*WF_)     /* 2816 */
#define MTOT   (BN*NQ)       /* 60000 */

typedef __attribute__((ext_vector_type(8))) unsigned short ushort8_t;
typedef __attribute__((ext_vector_type(8))) short bf16x8;
typedef __attribute__((ext_vector_type(4))) float f32x4;

static __device__ inline unsigned short f2bf(float x) {
    __hip_bfloat16 b = __float2bfloat16(x);
    return *(unsigned short*)&b;
}

// ---------------------------------------------------------------------------
// K_wcvt: f32 weights -> bf16 copies (Wv, [Wo;Wa]).
// ---------------------------------------------------------------------------
__global__ __launch_bounds__(256)
void k_wcvt(const float* __restrict__ Wv, const float* __restrict__ Wo,
            const float* __restrict__ Wa,
            unsigned short* __restrict__ Wv_bf, unsigned short* __restrict__ Woa_bf)
{
    const int i4 = (blockIdx.x*256 + threadIdx.x) * 4;
    if (i4 < 65536) {
        float4 v = *(const float4*)(Wv+i4);
        ushort4 p; p.x=f2bf(v.x);p.y=f2bf(v.y);p.z=f2bf(v.z);p.w=f2bf(v.w);
        *(ushort4*)(Wv_bf+i4) = p;
    }
    if (i4 < 32768) {
        float4 v = *(const float4*)(Wo+i4);
        ushort4 p; p.x=f2bf(v.x);p.y=f2bf(v.y);p.z=f2bf(v.z);p.w=f2bf(v.w);
        *(ushort4*)(Woa_bf+i4) = p;
    }
    if (i4 < 16384) {
        float4 v = *(const float4*)(Wa+i4);
        ushort4 p; p.x=f2bf(v.x);p.y=f2bf(v.y);p.z=f2bf(v.z);p.w=f2bf(v.w);
        *(ushort4*)(Woa_bf+32768+i4) = p;
    }
}

// ---------------------------------------------------------------------------
// K_wcomb: Wzi[j][k] = sum_t Wz[j][t]*Wi[t][k]  (bf16 out);
//          bzi[j]    = sum_t Wz[j][t]*bi[t].
// One block per j; Wi reads coalesced across k.
// ---------------------------------------------------------------------------
__global__ __launch_bounds__(256)
void k_wcomb(const float* __restrict__ Wz, const float* __restrict__ Wi,
             const float* __restrict__ bi,
             unsigned short* __restrict__ Wzi_bf, float* __restrict__ bzi)
{
    const int j = blockIdx.x;
    const int k = threadIdx.x;
    __shared__ float wzr[DIM];
    wzr[k] = Wz[(size_t)j*DIM + k];
    __syncthreads();
    float s = 0.f;
    for (int t = 0; t < DIM; ++t) s += wzr[t] * Wi[(size_t)t*DIM + k];
    Wzi_bf[(size_t)j*DIM + k] = f2bf(s);
    if (k == 0) {
        float b = 0.f;
        for (int t = 0; t < DIM; ++t) b += wzr[t] * bi[t];
        bzi[j] = b;
    }
}

// ---------------------------------------------------------------------------
// K0: ebias[n][j] = sum_d (lvl[d]+cam[n][d]) * W_value[j][d] + b_value[j]
// ---------------------------------------------------------------------------
__global__ __launch_bounds__(256)
void k_ebias(const float* __restrict__ lvl, const float* __restrict__ cam,
             const float* __restrict__ Wv, const float* __restrict__ bv,
             float* __restrict__ ebias)
{
    const int n = blockIdx.x;
    const int j = threadIdx.x;
    __shared__ float e[DIM];
    e[j] = lvl[j] + cam[n*DIM + j];
    __syncthreads();
    const float* w = Wv + (size_t)j*DIM;
    float s = bv[j];
    for (int d = 0; d < DIM; ++d) s += e[d]*w[d];
    ebias[n*DIM + j] = s;
}

// ---------------------------------------------------------------------------
// K_mask: per-q hit flags, count scale, bias gate.
// ---------------------------------------------------------------------------
__global__ __launch_bounds__(256)
void k_mask(const int* __restrict__ bev, float* __restrict__ hitf,
            float* __restrict__ scale, float* __restrict__ biasf)
{
    const int q = blockIdx.x*256 + threadIdx.x;
    if (q >= NQ) return;
    float cnt = 0.f;
    #pragma unroll
    for (int n = 0; n < BN; ++n) {
        int hit = 0;
        #pragma unroll
        for (int z = 0; z < 4; ++z)
            hit |= (bev[(((size_t)n*NQ + q)*4 + z)*2] != 0);
        hitf[(size_t)n*NQ + q] = (float)hit;
        cnt += (float)hit;
    }
    biasf[q] = (cnt > 0.f) ? 1.f : 0.f;
    scale[q] = 1.f / fmaxf(cnt, 1.f);
}

// ---------------------------------------------------------------------------
// K_feat: transpose feat[cam][256 d][2816 p] f32 -> featT[cam][p][d] bf16.
// ---------------------------------------------------------------------------
__global__ __launch_bounds__(256)
void k_feat(const float* __restrict__ feat, unsigned short* __restrict__ featT)
{
    __shared__ float Tf[64][68];
    const int cam = blockIdx.z;
    const int d0 = blockIdx.y * 64;
    const int p0 = blockIdx.x * 64;
    const int tid = threadIdx.x;
    #pragma unroll
    for (int i = 0; i < 4; ++i) {
        const int d = (tid>>4) + i*16;
        const int p4 = (tid&15)*4;
        *(float4*)&Tf[d][p4] = *(const float4*)(feat + ((size_t)cam*DIM + d0 + d)*HW_ + p0 + p4);
    }
    __syncthreads();
    const int p = tid>>2, dq = tid&3;
    unsigned short* ob = featT + ((size_t)cam*HW_ + p0 + p)*DIM + d0;
    #pragma unroll
    for (int i = 0; i < 4; ++i) {
        const int d4 = dq*4 + i*16;
        ushort4 pk;
        pk.x = f2bf(Tf[d4+0][p]); pk.y = f2bf(Tf[d4+1][p]);
        pk.z = f2bf(Tf[d4+2][p]); pk.w = f2bf(Tf[d4+3][p]);
        *(ushort4*)(ob + d4) = pk;
    }
}

// ---------------------------------------------------------------------------
// K1: value GEMM via MFMA (LDS-tiled, 528 blocks).
// ---------------------------------------------------------------------------
__global__ __launch_bounds__(256)
void k_value_mfma(const unsigned short* __restrict__ featT,
                  const unsigned short* __restrict__ Wv_bf,
                  const float* __restrict__ ebias,
                  unsigned short* __restrict__ value_bf)
{
    __shared__ unsigned short Ap[128][72];
    __shared__ unsigned short Bc[64][72];
    const int cam = blockIdx.z;
    const int p0 = blockIdx.x * 128;
    const int c0 = blockIdx.y * 64;
    const int tid = threadIdx.x;
    const int lane = tid & 63, wave = tid >> 6;
    const int quad = lane >> 4, l15 = lane & 15;
    f32x4 acc[2][4] = {};
    const unsigned short* fbase = featT + ((size_t)cam*HW_ + p0)*DIM;

    for (int k0 = 0; k0 < DIM; k0 += 64) {
        #pragma unroll
        for (int i = 0; i < 4; ++i) {
            const int row = (tid>>3) + i*32;
            const int k8 = (tid&7)*8;
            *(ushort8_t*)&Ap[row][k8] = *(const ushort8_t*)(fbase + (size_t)row*DIM + k0 + k8);
        }
        #pragma unroll
        for (int i = 0; i < 2; ++i) {
            const int row = (tid>>3) + i*32;
            const int k8 = (tid&7)*8;
            *(ushort8_t*)&Bc[row][k8] = *(const ushort8_t*)(Wv_bf + (size_t)(c0+row)*DIM + k0 + k8);
        }
        __syncthreads();
        #pragma unroll
        for (int s = 0; s < 2; ++s) {
            const int kf = s*32 + quad*8;
            bf16x8 a[2], b[4];
            #pragma unroll
            for (int mt = 0; mt < 2; ++mt)
                a[mt] = *(const bf16x8*)&Ap[(wave*2+mt)*16 + l15][kf];
            #pragma unroll
            for (int nt = 0; nt < 4; ++nt)
                b[nt] = *(const bf16x8*)&Bc[nt*16 + l15][kf];
            #pragma unroll
            for (int mt = 0; mt < 2; ++mt)
                #pragma unroll
                for (int nt = 0; nt < 4; ++nt)
                    acc[mt][nt] = __builtin_amdgcn_mfma_f32_16x16x32_bf16(a[mt], b[nt], acc[mt][nt], 0,0,0);
        }
        __syncthreads();
    }
    #pragma unroll
    for (int nt = 0; nt < 4; ++nt) {
        const int c = c0 + nt*16 + l15;
        const float eb = ebias[cam*DIM + c];
        const int h = c >> 5, cc = c & 31;
        unsigned short* vb = value_bf + (size_t)(cam*HEADS + h)*HW_*HDD + cc;
        #pragma unroll
        for (int mt = 0; mt < 2; ++mt)
            #pragma unroll
            for (int r = 0; r < 4; ++r) {
                const int p = p0 + (wave*2+mt)*16 + quad*4 + r;
                vb[(size_t)p*HDD] = f2bf(acc[mt][nt][r] + eb);
            }
    }
}

// ---------------------------------------------------------------------------
// K2a: off/attn GEMM, barrier-free, register-pipelined.
// 16-row m-tile per wave; A in VGPRs; B double-buffered from L2.
// __launch_bounds__(256,2): ~256 VGPR budget so 12 B-loads stay in flight.
// ---------------------------------------------------------------------------
__global__ __launch_bounds__(256, 2)
void k_offattn(const float* __restrict__ Qr, const float* __restrict__ Pe,
               const unsigned short* __restrict__ Woa_bf,
               const float* __restrict__ boff, const float* __restrict__ battn,
               float* __restrict__ off_ws, float* __restrict__ attw_ws)
{
    const int tid = threadIdx.x;
    const int wave = tid >> 6, lane = tid & 63;
    const int quad = lane >> 4, l15 = lane & 15;
    const int m0 = (blockIdx.x*4 + wave) * 16;
    if (m0 >= MTOT) return;

    // ---- A fragments: row = m0+l15, frag kc covers k = kc*32 + quad*8
    bf16x8 afr[8];
    {
        const float* qrow = Qr + (size_t)(m0 + l15)*DIM;
        const float* prow = Pe + (size_t)(m0 + l15)*DIM;
        #pragma unroll
        for (int kc = 0; kc < 8; ++kc) {
            const int k = kc*32 + quad*8;
            const float4 x0 = *(const float4*)(qrow + k);
            const float4 x1 = *(const float4*)(qrow + k + 4);
            const float4 y0 = *(const float4*)(prow + k);
            const float4 y1 = *(const float4*)(prow + k + 4);
            ushort8_t u;
            u[0]=f2bf(x0.x+y0.x); u[1]=f2bf(x0.y+y0.y); u[2]=f2bf(x0.z+y0.z); u[3]=f2bf(x0.w+y0.w);
            u[4]=f2bf(x1.x+y1.x); u[5]=f2bf(x1.y+y1.y); u[6]=f2bf(x1.z+y1.z); u[7]=f2bf(x1.w+y1.w);
            afr[kc] = *(bf16x8*)&u;
        }
    }

    // ---- K-loop: B frags double-buffered from L2 (98 KB, fully resident)
    f32x4 acc[12] = {};
    const unsigned short* bbase = Woa_bf + (size_t)l15*DIM + quad*8;
    bf16x8 bcur[12], bnxt[12];
    #pragma unroll
    for (int nt = 0; nt < 12; ++nt)
        bcur[nt] = *(const bf16x8*)(bbase + (size_t)nt*16*DIM);
    #pragma unroll
    for (int kc = 0; kc < 8; ++kc) {
        if (kc < 7) {
            #pragma unroll
            for (int nt = 0; nt < 12; ++nt)
                bnxt[nt] = *(const bf16x8*)(bbase + (size_t)nt*16*DIM + (kc+1)*32);
        }
        #pragma unroll
        for (int nt = 0; nt < 12; ++nt)
            acc[nt] = __builtin_amdgcn_mfma_f32_16x16x32_bf16(afr[kc], bcur[nt], acc[nt], 0,0,0);
        #pragma unroll
        for (int nt = 0; nt < 12; ++nt) bcur[nt] = bnxt[nt];
    }

    // ---- epilogue: C layout col=l15, row=quad*4+r
    #pragma unroll
    for (int nt = 0; nt < 12; ++nt) {
        const int col = nt*16 + l15;
        const float bias = (col < 128) ? boff[col] : battn[col-128];
        #pragma unroll
        for (int r = 0; r < 4; ++r) {
            const int m = m0 + quad*4 + r;
            const float v = acc[nt][r] + bias;
            if (col < 128) off_ws [(size_t)m*128 + col]      = v;
            else           attw_ws[(size_t)m*64 + (col-128)] = v;
        }
    }
}

// ---------------------------------------------------------------------------
// K2b: sampling fused with camera reduce — barrier-free, batched gathers.
// __launch_bounds__(256,4): 128-VGPR cap, room to pipeline corner loads.
// ---------------------------------------------------------------------------
__global__ __launch_bounds__(256, 4)
void k_sample(const unsigned short* __restrict__ value_bf,
              const float* __restrict__ off_ws, const float* __restrict__ attw_ws,
              const float* __restrict__ ref3d, const float* __restrict__ hitf,
              const float* __restrict__ scale, unsigned short* __restrict__ asum_bf)
{
    const int gtid = blockIdx.x*256 + threadIdx.x;   // 320000 threads
    const int quarter = gtid & 3;
    const int h  = (gtid >> 2) & 7;
    const int q  = gtid >> 5;

    float acc[8];
    #pragma unroll
    for (int c = 0; c < 8; ++c) acc[c] = 0.f;

    #pragma unroll 1
    for (int n = 0; n < BN; ++n) {
        if (hitf[(size_t)n*NQ + q] == 0.f) continue;
        const size_t base = (size_t)n*NQ + q;

        const float4 a0 = *(const float4*)(attw_ws + base*64 + h*8);
        const float4 a1 = *(const float4*)(attw_ws + base*64 + h*8 + 4);
        float lg[8] = {a0.x,a0.y,a0.z,a0.w, a1.x,a1.y,a1.z,a1.w};
        float mx = -1e30f;
        #pragma unroll
        for (int p = 0; p < 8; ++p) mx = fmaxf(mx, lg[p]);
        float ssum = 0.f;
        #pragma unroll
        for (int p = 0; p < 8; ++p) { lg[p] = __expf(lg[p]-mx); ssum += lg[p]; }
        const float inv = 1.f/ssum;

        float off[16];
        #pragma unroll
        for (int i = 0; i < 4; ++i)
            *(float4*)&off[i*4] = *(const float4*)(off_ws + base*128 + h*16 + i*4);
        float ref[8];
        *(float4*)&ref[0] = *(const float4*)(ref3d + base*8);
        *(float4*)&ref[4] = *(const float4*)(ref3d + base*8 + 4);

        const unsigned short* vbase =
            value_bf + (size_t)(n*HEADS + h)*HW_*HDD + quarter*8;

        #pragma unroll
        for (int p = 0; p < 8; ++p) {
            const int z = p & 3;
            const float ax = ref[z*2+0]*WF_ + off[p*2+0] - 0.5f;
            const float ay = ref[z*2+1]*HF_ + off[p*2+1] - 0.5f;
            const float fx = floorf(ax), fy = floorf(ay);
            const float dx = ax-fx, dy = ay-fy;
            const int x0 = (int)fx, y0 = (int)fy;
            const float wp = lg[p]*inv;

            // corner addresses + weights first, then batched loads, then FMAs
            int   cidx[4];
            float cw[4];
            #pragma unroll
            for (int cc = 0; cc < 4; ++cc) {
                const int oy = cc >> 1, ox = cc & 1;
                const int yi = y0 + oy, xi = x0 + ox;
                const float wgt = (oy ? dy : 1.f-dy) * (ox ? dx : 1.f-dx);
                const bool valid = ((unsigned)xi < WF_) & ((unsigned)yi < HF_);
                cw[cc]   = valid ? wp*wgt : 0.f;
                cidx[cc] = min(max(yi,0), HF_-1)*WF_ + min(max(xi,0), WF_-1);
            }
            ushort8_t v[4];
            #pragma unroll
            for (int cc = 0; cc < 4; ++cc)
                v[cc] = *(const ushort8_t*)(vbase + (size_t)cidx[cc]*HDD);
            #pragma unroll
            for (int cc = 0; cc < 4; ++cc)
                #pragma unroll
                for (int c = 0; c < 8; ++c)
                    acc[c] += cw[cc] * __uint_as_float(((unsigned)v[cc][c]) << 16);
        }
    }

    const float sc = scale[q];
    ushort8_t o;
    #pragma unroll
    for (int c = 0; c < 8; ++c) o[c] = f2bf(acc[c]*sc);
    *(ushort8_t*)(asum_bf + (size_t)q*DIM + h*HDD + quarter*8) = o;
}

// ---------------------------------------------------------------------------
// K3: MFMA GEMM 128m x 64n: out = A_bf·W_bf^T + f(m)*b1[j] + b2[j].
// ---------------------------------------------------------------------------
__global__ __launch_bounds__(256)
void k_gemm_mfma(const unsigned short* __restrict__ A_bf,
                 const unsigned short* __restrict__ W_bf,
                 const float* __restrict__ b1, const float* __restrict__ rowscale,
                 const float* __restrict__ b2,
                 float* __restrict__ out_f, int M)
{
    __shared__ unsigned short As[128][72];
    __shared__ unsigned short Bs[64][72];
    const int m0 = blockIdx.x * 128;
    const int j0 = blockIdx.y * 64;
    const int tid = threadIdx.x;
    const int lane = tid & 63, wave = tid >> 6;
    const int quad = lane >> 4, l15 = lane & 15;
    f32x4 acc[2][4] = {};

    for (int k0 = 0; k0 < DIM; k0 += 64) {
        #pragma unroll
        for (int i = 0; i < 4; ++i) {
            const int row = (tid>>3) + i*32;
            const int k8 = (tid&7)*8;
            ushort8_t v = {0,0,0,0,0,0,0,0};
            if (m0 + row < M)
                v = *(const ushort8_t*)(A_bf + (size_t)(m0+row)*DIM + k0 + k8);
            *(ushort8_t*)&As[row][k8] = v;
        }
        #pragma unroll
        for (int i = 0; i < 2; ++i) {
            const int row = (tid>>3) + i*32;
            const int k8 = (tid&7)*8;
            *(ushort8_t*)&Bs[row][k8] = *(const ushort8_t*)(W_bf + (size_t)(j0+row)*DIM + k0 + k8);
        }
        __syncthreads();
        #pragma unroll
        for (int s = 0; s < 2; ++s) {
            const int kf = s*32 + quad*8;
            bf16x8 a[2], b[4];
            #pragma unroll
            for (int mt = 0; mt < 2; ++mt)
                a[mt] = *(const bf16x8*)&As[(wave*2+mt)*16 + l15][kf];
            #pragma unroll
            for (int nt = 0; nt < 4; ++nt)
                b[nt] = *(const bf16x8*)&Bs[nt*16 + l15][kf];
            #pragma unroll
            for (int mt = 0; mt < 2; ++mt)
                #pragma unroll
                for (int nt = 0; nt < 4; ++nt)
                    acc[mt][nt] = __builtin_amdgcn_mfma_f32_16x16x32_bf16(a[mt], b[nt], acc[mt][nt], 0,0,0);
        }
        __syncthreads();
    }
    #pragma unroll
    for (int nt = 0; nt < 4; ++nt) {
        const int j = j0 + nt*16 + l15;
        const float b1j = b1[j], b2j = b2[j];
        #pragma unroll
        for (int mt = 0; mt < 2; ++mt) {
            #pragma unroll
            for (int r = 0; r < 4; ++r) {
                const int m = m0 + (wave*2+mt)*16 + quad*4 + r;
                if (m >= M) continue;
                out_f[(size_t)m*DIM + j] = acc[mt][nt][r] + rowscale[m]*b1j + b2j;
            }
        }
    }
}

// ---------------------------------------------------------------------------
extern "C" void kernel_launch(void* const* d_in, const int* in_sizes, int n_in,
                              void* d_out, int out_size, void* d_ws, size_t ws_size,
                              hipStream_t stream)
{
    const float* queries = (const float*)d_in[0];
    const float* pos_emb = (const float*)d_in[1];
    const float* lvl_emb = (const float*)d_in[2];
    const float* cam_emb = (const float*)d_in[3];
    const float* features= (const float*)d_in[4];
    const float* ref3d   = (const float*)d_in[5];
    const int*   bev     = (const int*)d_in[6];
    const float* Wv = (const float*)d_in[7];
    const float* bv = (const float*)d_in[8];
    const float* Wo = (const float*)d_in[9];
    const float* bo = (const float*)d_in[10];
    const float* Wa = (const float*)d_in[11];
    const float* ba = (const float*)d_in[12];
    const float* Wi = (const float*)d_in[13];
    const float* bi = (const float*)d_in[14];
    const float* Wz = (const float*)d_in[15];
    const float* bz = (const float*)d_in[16];
    float* out = (float*)d_out;

    char* ws = (char*)d_ws;
    size_t o = 0;
    auto alloc = [&](size_t bytes) { char* p = ws + o; o += (bytes + 255) & ~size_t(255); return p; };
    unsigned short* value_bf = (unsigned short*)alloc((size_t)BN*HEADS*HW_*HDD*2);
    unsigned short* featT    = (unsigned short*)alloc((size_t)BN*HW_*DIM*2);
    float* off_ws   = (float*)alloc((size_t)MTOT*128*4);
    float* attw_ws  = (float*)alloc((size_t)MTOT*64*4);
    unsigned short* asum_bf  = (unsigned short*)alloc((size_t)NQ*DIM*2);
    unsigned short* Wv_bf  = (unsigned short*)alloc(65536*2);
    unsigned short* Woa_bf = (unsigned short*)alloc(49152*2);
    unsigned short* Wzi_bf = (unsigned short*)alloc(65536*2);
    float* bzi    = (float*)alloc(DIM*4);
    float* hitf   = (float*)alloc((size_t)BN*NQ*4);
    float* scalev = (float*)alloc(NQ*4);
    float* biasf  = (float*)alloc(NQ*4);
    float* ebias  = (float*)alloc(BN*DIM*4);

    k_wcvt  <<<64, 256, 0, stream>>>(Wv, Wo, Wa, Wv_bf, Woa_bf);
    k_wcomb <<<DIM, 256, 0, stream>>>(Wz, Wi, bi, Wzi_bf, bzi);
    k_ebias <<<BN, 256, 0, stream>>>(lvl_emb, cam_emb, Wv, bv, ebias);
    k_mask  <<<(NQ+255)/256, 256, 0, stream>>>(bev, hitf, scalev, biasf);
    k_feat  <<<dim3(HW_/64, DIM/64, BN), 256, 0, stream>>>(features, featT);
    k_value_mfma<<<dim3(HW_/128, DIM/64, BN), 256, 0, stream>>>(featT, Wv_bf, ebias, value_bf);
    k_offattn<<<(MTOT/16 + 3)/4, 256, 0, stream>>>(queries, pos_emb, Woa_bf, bo, ba, off_ws, attw_ws);
    k_sample <<<NQ*32/256, 256, 0, stream>>>(value_bf, off_ws, attw_ws, ref3d, hitf, scalev, asum_bf);
    k_gemm_mfma<<<dim3((NQ+127)/128, DIM/64), 256, 0, stream>>>(asum_bf, Wzi_bf, bzi, biasf, bz, out, NQ);
}

// Round 7
// 372.228 us; speedup vs baseline: 1.6537x; 1.6537x over previous
//
#include <hip/hip_runtime.h>
#include <hip/hip_bf16.h>

#define BN     6
#define NQ     10000
#define DIM    256
#define HEADS  8
#define HDD    32
#define HF_    32
#define WF_    88
#define HW_    (HF_*WF_)     /* 2816 */
#define MTOT   (BN*NQ)       /* 60000 */

typedef __attribute__((ext_vector_type(8))) unsigned short ushort8_t;
typedef __attribute__((ext_vector_type(8))) short bf16x8;
typedef __attribute__((ext_vector_type(4))) float f32x4;

static __device__ inline unsigned short f2bf(float x) {
    __hip_bfloat16 b = __float2bfloat16(x);
    return *(unsigned short*)&b;
}

// ---------------------------------------------------------------------------
// K_wcvt: f32 weights -> bf16 copies (Wv, [Wo;Wa]).
// ---------------------------------------------------------------------------
__global__ __launch_bounds__(256)
void k_wcvt(const float* __restrict__ Wv, const float* __restrict__ Wo,
            const float* __restrict__ Wa,
            unsigned short* __restrict__ Wv_bf, unsigned short* __restrict__ Woa_bf)
{
    const int i4 = (blockIdx.x*256 + threadIdx.x) * 4;
    if (i4 < 65536) {
        float4 v = *(const float4*)(Wv+i4);
        ushort4 p; p.x=f2bf(v.x);p.y=f2bf(v.y);p.z=f2bf(v.z);p.w=f2bf(v.w);
        *(ushort4*)(Wv_bf+i4) = p;
    }
    if (i4 < 32768) {
        float4 v = *(const float4*)(Wo+i4);
        ushort4 p; p.x=f2bf(v.x);p.y=f2bf(v.y);p.z=f2bf(v.z);p.w=f2bf(v.w);
        *(ushort4*)(Woa_bf+i4) = p;
    }
    if (i4 < 16384) {
        float4 v = *(const float4*)(Wa+i4);
        ushort4 p; p.x=f2bf(v.x);p.y=f2bf(v.y);p.z=f2bf(v.z);p.w=f2bf(v.w);
        *(ushort4*)(Woa_bf+32768+i4) = p;
    }
}

// ---------------------------------------------------------------------------
// K_wcomb: Wzi[j][k] = sum_t Wz[j][t]*Wi[t][k]  (bf16 out);
//          bzi[j]    = sum_t Wz[j][t]*bi[t].
// ---------------------------------------------------------------------------
__global__ __launch_bounds__(256)
void k_wcomb(const float* __restrict__ Wz, const float* __restrict__ Wi,
             const float* __restrict__ bi,
             unsigned short* __restrict__ Wzi_bf, float* __restrict__ bzi)
{
    const int j = blockIdx.x;
    const int k = threadIdx.x;
    __shared__ float wzr[DIM];
    wzr[k] = Wz[(size_t)j*DIM + k];
    __syncthreads();
    float s = 0.f;
    for (int t = 0; t < DIM; ++t) s += wzr[t] * Wi[(size_t)t*DIM + k];
    Wzi_bf[(size_t)j*DIM + k] = f2bf(s);
    if (k == 0) {
        float b = 0.f;
        for (int t = 0; t < DIM; ++t) b += wzr[t] * bi[t];
        bzi[j] = b;
    }
}

// ---------------------------------------------------------------------------
// K0: ebias[n][j] = sum_d (lvl[d]+cam[n][d]) * W_value[j][d] + b_value[j]
// ---------------------------------------------------------------------------
__global__ __launch_bounds__(256)
void k_ebias(const float* __restrict__ lvl, const float* __restrict__ cam,
             const float* __restrict__ Wv, const float* __restrict__ bv,
             float* __restrict__ ebias)
{
    const int n = blockIdx.x;
    const int j = threadIdx.x;
    __shared__ float e[DIM];
    e[j] = lvl[j] + cam[n*DIM + j];
    __syncthreads();
    const float* w = Wv + (size_t)j*DIM;
    float s = bv[j];
    for (int d = 0; d < DIM; ++d) s += e[d]*w[d];
    ebias[n*DIM + j] = s;
}

// ---------------------------------------------------------------------------
// K_mask: per-q hit flags, count scale, bias gate.
// ---------------------------------------------------------------------------
__global__ __launch_bounds__(256)
void k_mask(const int* __restrict__ bev, float* __restrict__ hitf,
            float* __restrict__ scale, float* __restrict__ biasf)
{
    const int q = blockIdx.x*256 + threadIdx.x;
    if (q >= NQ) return;
    float cnt = 0.f;
    #pragma unroll
    for (int n = 0; n < BN; ++n) {
        int hit = 0;
        #pragma unroll
        for (int z = 0; z < 4; ++z)
            hit |= (bev[(((size_t)n*NQ + q)*4 + z)*2] != 0);
        hitf[(size_t)n*NQ + q] = (float)hit;
        cnt += (float)hit;
    }
    biasf[q] = (cnt > 0.f) ? 1.f : 0.f;
    scale[q] = 1.f / fmaxf(cnt, 1.f);
}

// ---------------------------------------------------------------------------
// K_feat: transpose feat[cam][256 d][2816 p] f32 -> featT[cam][p][d] bf16.
// ---------------------------------------------------------------------------
__global__ __launch_bounds__(256)
void k_feat(const float* __restrict__ feat, unsigned short* __restrict__ featT)
{
    __shared__ float Tf[64][68];
    const int cam = blockIdx.z;
    const int d0 = blockIdx.y * 64;
    const int p0 = blockIdx.x * 64;
    const int tid = threadIdx.x;
    #pragma unroll
    for (int i = 0; i < 4; ++i) {
        const int d = (tid>>4) + i*16;
        const int p4 = (tid&15)*4;
        *(float4*)&Tf[d][p4] = *(const float4*)(feat + ((size_t)cam*DIM + d0 + d)*HW_ + p0 + p4);
    }
    __syncthreads();
    const int p = tid>>2, dq = tid&3;
    unsigned short* ob = featT + ((size_t)cam*HW_ + p0 + p)*DIM + d0;
    #pragma unroll
    for (int i = 0; i < 4; ++i) {
        const int d4 = dq*4 + i*16;
        ushort4 pk;
        pk.x = f2bf(Tf[d4+0][p]); pk.y = f2bf(Tf[d4+1][p]);
        pk.z = f2bf(Tf[d4+2][p]); pk.w = f2bf(Tf[d4+3][p]);
        *(ushort4*)(ob + d4) = pk;
    }
}

// ---------------------------------------------------------------------------
// K1: value GEMM via MFMA (LDS-tiled, 528 blocks).
// ---------------------------------------------------------------------------
__global__ __launch_bounds__(256)
void k_value_mfma(const unsigned short* __restrict__ featT,
                  const unsigned short* __restrict__ Wv_bf,
                  const float* __restrict__ ebias,
                  unsigned short* __restrict__ value_bf)
{
    __shared__ unsigned short Ap[128][72];
    __shared__ unsigned short Bc[64][72];
    const int cam = blockIdx.z;
    const int p0 = blockIdx.x * 128;
    const int c0 = blockIdx.y * 64;
    const int tid = threadIdx.x;
    const int lane = tid & 63, wave = tid >> 6;
    const int quad = lane >> 4, l15 = lane & 15;
    f32x4 acc[2][4] = {};
    const unsigned short* fbase = featT + ((size_t)cam*HW_ + p0)*DIM;

    for (int k0 = 0; k0 < DIM; k0 += 64) {
        #pragma unroll
        for (int i = 0; i < 4; ++i) {
            const int row = (tid>>3) + i*32;
            const int k8 = (tid&7)*8;
            *(ushort8_t*)&Ap[row][k8] = *(const ushort8_t*)(fbase + (size_t)row*DIM + k0 + k8);
        }
        #pragma unroll
        for (int i = 0; i < 2; ++i) {
            const int row = (tid>>3) + i*32;
            const int k8 = (tid&7)*8;
            *(ushort8_t*)&Bc[row][k8] = *(const ushort8_t*)(Wv_bf + (size_t)(c0+row)*DIM + k0 + k8);
        }
        __syncthreads();
        #pragma unroll
        for (int s = 0; s < 2; ++s) {
            const int kf = s*32 + quad*8;
            bf16x8 a[2], b[4];
            #pragma unroll
            for (int mt = 0; mt < 2; ++mt)
                a[mt] = *(const bf16x8*)&Ap[(wave*2+mt)*16 + l15][kf];
            #pragma unroll
            for (int nt = 0; nt < 4; ++nt)
                b[nt] = *(const bf16x8*)&Bc[nt*16 + l15][kf];
            #pragma unroll
            for (int mt = 0; mt < 2; ++mt)
                #pragma unroll
                for (int nt = 0; nt < 4; ++nt)
                    acc[mt][nt] = __builtin_amdgcn_mfma_f32_16x16x32_bf16(a[mt], b[nt], acc[mt][nt], 0,0,0);
        }
        __syncthreads();
    }
    #pragma unroll
    for (int nt = 0; nt < 4; ++nt) {
        const int c = c0 + nt*16 + l15;
        const float eb = ebias[cam*DIM + c];
        const int h = c >> 5, cc = c & 31;
        unsigned short* vb = value_bf + (size_t)(cam*HEADS + h)*HW_*HDD + cc;
        #pragma unroll
        for (int mt = 0; mt < 2; ++mt)
            #pragma unroll
            for (int r = 0; r < 4; ++r) {
                const int p = p0 + (wave*2+mt)*16 + quad*4 + r;
                vb[(size_t)p*HDD] = f2bf(acc[mt][nt][r] + eb);
            }
    }
}

// ---------------------------------------------------------------------------
// K2a: off/attn GEMM, barrier-free, register-pipelined.
// 16-row m-tile per wave; A in VGPRs; B double-buffered from L2.
// ---------------------------------------------------------------------------
__global__ __launch_bounds__(256, 2)
void k_offattn(const float* __restrict__ Qr, const float* __restrict__ Pe,
               const unsigned short* __restrict__ Woa_bf,
               const float* __restrict__ boff, const float* __restrict__ battn,
               float* __restrict__ off_ws, float* __restrict__ attw_ws)
{
    const int tid = threadIdx.x;
    const int wave = tid >> 6, lane = tid & 63;
    const int quad = lane >> 4, l15 = lane & 15;
    const int m0 = (blockIdx.x*4 + wave) * 16;
    if (m0 >= MTOT) return;

    // ---- A fragments: row = m0+l15, frag kc covers k = kc*32 + quad*8
    bf16x8 afr[8];
    {
        const float* qrow = Qr + (size_t)(m0 + l15)*DIM;
        const float* prow = Pe + (size_t)(m0 + l15)*DIM;
        #pragma unroll
        for (int kc = 0; kc < 8; ++kc) {
            const int k = kc*32 + quad*8;
            const float4 x0 = *(const float4*)(qrow + k);
            const float4 x1 = *(const float4*)(qrow + k + 4);
            const float4 y0 = *(const float4*)(prow + k);
            const float4 y1 = *(const float4*)(prow + k + 4);
            ushort8_t u;
            u[0]=f2bf(x0.x+y0.x); u[1]=f2bf(x0.y+y0.y); u[2]=f2bf(x0.z+y0.z); u[3]=f2bf(x0.w+y0.w);
            u[4]=f2bf(x1.x+y1.x); u[5]=f2bf(x1.y+y1.y); u[6]=f2bf(x1.z+y1.z); u[7]=f2bf(x1.w+y1.w);
            afr[kc] = *(bf16x8*)&u;
        }
    }

    // ---- K-loop: B frags double-buffered from L2 (98 KB, fully resident)
    f32x4 acc[12] = {};
    const unsigned short* bbase = Woa_bf + (size_t)l15*DIM + quad*8;
    bf16x8 bcur[12], bnxt[12];
    #pragma unroll
    for (int nt = 0; nt < 12; ++nt)
        bcur[nt] = *(const bf16x8*)(bbase + (size_t)nt*16*DIM);
    #pragma unroll
    for (int kc = 0; kc < 8; ++kc) {
        if (kc < 7) {
            #pragma unroll
            for (int nt = 0; nt < 12; ++nt)
                bnxt[nt] = *(const bf16x8*)(bbase + (size_t)nt*16*DIM + (kc+1)*32);
        }
        #pragma unroll
        for (int nt = 0; nt < 12; ++nt)
            acc[nt] = __builtin_amdgcn_mfma_f32_16x16x32_bf16(afr[kc], bcur[nt], acc[nt], 0,0,0);
        #pragma unroll
        for (int nt = 0; nt < 12; ++nt) bcur[nt] = bnxt[nt];
    }

    // ---- epilogue: C layout col=l15, row=quad*4+r
    #pragma unroll
    for (int nt = 0; nt < 12; ++nt) {
        const int col = nt*16 + l15;
        const float bias = (col < 128) ? boff[col] : battn[col-128];
        #pragma unroll
        for (int r = 0; r < 4; ++r) {
            const int m = m0 + quad*4 + r;
            const float v = acc[nt][r] + bias;
            if (col < 128) off_ws [(size_t)m*128 + col]      = v;
            else           attw_ws[(size_t)m*64 + (col-128)] = v;
        }
    }
}

// ---------------------------------------------------------------------------
// K2b: sampling fused with camera reduce — barrier-free (R5 body; no
// waves-per-EU floor: the (256,4) cap caused 624 MB of scratch spill in R6).
// ---------------------------------------------------------------------------
__global__ __launch_bounds__(256)
void k_sample(const unsigned short* __restrict__ value_bf,
              const float* __restrict__ off_ws, const float* __restrict__ attw_ws,
              const float* __restrict__ ref3d, const float* __restrict__ hitf,
              const float* __restrict__ scale, unsigned short* __restrict__ asum_bf)
{
    const int gtid = blockIdx.x*256 + threadIdx.x;   // 320000 threads
    const int quarter = gtid & 3;
    const int h  = (gtid >> 2) & 7;
    const int q  = gtid >> 5;

    float acc[8];
    #pragma unroll
    for (int c = 0; c < 8; ++c) acc[c] = 0.f;

    #pragma unroll 1
    for (int n = 0; n < BN; ++n) {
        if (hitf[(size_t)n*NQ + q] == 0.f) continue;
        const size_t base = (size_t)n*NQ + q;

        const float4 a0 = *(const float4*)(attw_ws + base*64 + h*8);
        const float4 a1 = *(const float4*)(attw_ws + base*64 + h*8 + 4);
        float lg[8] = {a0.x,a0.y,a0.z,a0.w, a1.x,a1.y,a1.z,a1.w};
        float mx = -1e30f;
        #pragma unroll
        for (int p = 0; p < 8; ++p) mx = fmaxf(mx, lg[p]);
        float ssum = 0.f;
        #pragma unroll
        for (int p = 0; p < 8; ++p) { lg[p] = __expf(lg[p]-mx); ssum += lg[p]; }
        const float inv = 1.f/ssum;

        float off[16];
        #pragma unroll
        for (int i = 0; i < 4; ++i)
            *(float4*)&off[i*4] = *(const float4*)(off_ws + base*128 + h*16 + i*4);
        float ref[8];
        *(float4*)&ref[0] = *(const float4*)(ref3d + base*8);
        *(float4*)&ref[4] = *(const float4*)(ref3d + base*8 + 4);

        const unsigned short* vbase =
            value_bf + (size_t)(n*HEADS + h)*HW_*HDD + quarter*8;

        #pragma unroll
        for (int p = 0; p < 8; ++p) {
            const int z = p & 3;
            const float ax = ref[z*2+0]*WF_ + off[p*2+0] - 0.5f;
            const float ay = ref[z*2+1]*HF_ + off[p*2+1] - 0.5f;
            const float fx = floorf(ax), fy = floorf(ay);
            const float dx = ax-fx, dy = ay-fy;
            const int x0 = (int)fx, y0 = (int)fy;
            const float wp = lg[p]*inv;
            #pragma unroll
            for (int oy = 0; oy < 2; ++oy) {
                const int yi = y0 + oy;
                const float wy = oy ? dy : 1.f-dy;
                #pragma unroll
                for (int ox = 0; ox < 2; ++ox) {
                    const int xi = x0 + ox;
                    const float wx = ox ? dx : 1.f-dx;
                    const bool valid = ((unsigned)xi < WF_) & ((unsigned)yi < HF_);
                    const float cw = valid ? wp*wy*wx : 0.f;
                    const int xc = min(max(xi, 0), WF_-1);
                    const int yc = min(max(yi, 0), HF_-1);
                    const ushort8_t v = *(const ushort8_t*)(vbase + (size_t)(yc*WF_ + xc)*HDD);
                    #pragma unroll
                    for (int c = 0; c < 8; ++c)
                        acc[c] += cw * __uint_as_float(((unsigned)v[c]) << 16);
                }
            }
        }
    }

    const float sc = scale[q];
    ushort8_t o;
    #pragma unroll
    for (int c = 0; c < 8; ++c) o[c] = f2bf(acc[c]*sc);
    *(ushort8_t*)(asum_bf + (size_t)q*DIM + h*HDD + quarter*8) = o;
}

// ---------------------------------------------------------------------------
// K3: MFMA GEMM 128m x 64n: out = A_bf·Wzi^T + f(m)*bzi[j] + bz[j].
// ---------------------------------------------------------------------------
__global__ __launch_bounds__(256)
void k_gemm_mfma(const unsigned short* __restrict__ A_bf,
                 const unsigned short* __restrict__ W_bf,
                 const float* __restrict__ b1, const float* __restrict__ rowscale,
                 const float* __restrict__ b2,
                 float* __restrict__ out_f, int M)
{
    __shared__ unsigned short As[128][72];
    __shared__ unsigned short Bs[64][72];
    const int m0 = blockIdx.x * 128;
    const int j0 = blockIdx.y * 64;
    const int tid = threadIdx.x;
    const int lane = tid & 63, wave = tid >> 6;
    const int quad = lane >> 4, l15 = lane & 15;
    f32x4 acc[2][4] = {};

    for (int k0 = 0; k0 < DIM; k0 += 64) {
        #pragma unroll
        for (int i = 0; i < 4; ++i) {
            const int row = (tid>>3) + i*32;
            const int k8 = (tid&7)*8;
            ushort8_t v = {0,0,0,0,0,0,0,0};
            if (m0 + row < M)
                v = *(const ushort8_t*)(A_bf + (size_t)(m0+row)*DIM + k0 + k8);
            *(ushort8_t*)&As[row][k8] = v;
        }
        #pragma unroll
        for (int i = 0; i < 2; ++i) {
            const int row = (tid>>3) + i*32;
            const int k8 = (tid&7)*8;
            *(ushort8_t*)&Bs[row][k8] = *(const ushort8_t*)(W_bf + (size_t)(j0+row)*DIM + k0 + k8);
        }
        __syncthreads();
        #pragma unroll
        for (int s = 0; s < 2; ++s) {
            const int kf = s*32 + quad*8;
            bf16x8 a[2], b[4];
            #pragma unroll
            for (int mt = 0; mt < 2; ++mt)
                a[mt] = *(const bf16x8*)&As[(wave*2+mt)*16 + l15][kf];
            #pragma unroll
            for (int nt = 0; nt < 4; ++nt)
                b[nt] = *(const bf16x8*)&Bs[nt*16 + l15][kf];
            #pragma unroll
            for (int mt = 0; mt < 2; ++mt)
                #pragma unroll
                for (int nt = 0; nt < 4; ++nt)
                    acc[mt][nt] = __builtin_amdgcn_mfma_f32_16x16x32_bf16(a[mt], b[nt], acc[mt][nt], 0,0,0);
        }
        __syncthreads();
    }
    #pragma unroll
    for (int nt = 0; nt < 4; ++nt) {
        const int j = j0 + nt*16 + l15;
        const float b1j = b1[j], b2j = b2[j];
        #pragma unroll
        for (int mt = 0; mt < 2; ++mt) {
            #pragma unroll
            for (int r = 0; r < 4; ++r) {
                const int m = m0 + (wave*2+mt)*16 + quad*4 + r;
                if (m >= M) continue;
                out_f[(size_t)m*DIM + j] = acc[mt][nt][r] + rowscale[m]*b1j + b2j;
            }
        }
    }
}

// ---------------------------------------------------------------------------
extern "C" void kernel_launch(void* const* d_in, const int* in_sizes, int n_in,
                              void* d_out, int out_size, void* d_ws, size_t ws_size,
                              hipStream_t stream)
{
    const float* queries = (const float*)d_in[0];
    const float* pos_emb = (const float*)d_in[1];
    const float* lvl_emb = (const float*)d_in[2];
    const float* cam_emb = (const float*)d_in[3];
    const float* features= (const float*)d_in[4];
    const float* ref3d   = (const float*)d_in[5];
    const int*   bev     = (const int*)d_in[6];
    const float* Wv = (const float*)d_in[7];
    const float* bv = (const float*)d_in[8];
    const float* Wo = (const float*)d_in[9];
    const float* bo = (const float*)d_in[10];
    const float* Wa = (const float*)d_in[11];
    const float* ba = (const float*)d_in[12];
    const float* Wi = (const float*)d_in[13];
    const float* bi = (const float*)d_in[14];
    const float* Wz = (const float*)d_in[15];
    const float* bz = (const float*)d_in[16];
    float* out = (float*)d_out;

    char* ws = (char*)d_ws;
    size_t o = 0;
    auto alloc = [&](size_t bytes) { char* p = ws + o; o += (bytes + 255) & ~size_t(255); return p; };
    unsigned short* value_bf = (unsigned short*)alloc((size_t)BN*HEADS*HW_*HDD*2);
    unsigned short* featT    = (unsigned short*)alloc((size_t)BN*HW_*DIM*2);
    float* off_ws   = (float*)alloc((size_t)MTOT*128*4);
    float* attw_ws  = (float*)alloc((size_t)MTOT*64*4);
    unsigned short* asum_bf  = (unsigned short*)alloc((size_t)NQ*DIM*2);
    unsigned short* Wv_bf  = (unsigned short*)alloc(65536*2);
    unsigned short* Woa_bf = (unsigned short*)alloc(49152*2);
    unsigned short* Wzi_bf = (unsigned short*)alloc(65536*2);
    float* bzi    = (float*)alloc(DIM*4);
    float* hitf   = (float*)alloc((size_t)BN*NQ*4);
    float* scalev = (float*)alloc(NQ*4);
    float* biasf  = (float*)alloc(NQ*4);
    float* ebias  = (float*)alloc(BN*DIM*4);

    k_wcvt  <<<64, 256, 0, stream>>>(Wv, Wo, Wa, Wv_bf, Woa_bf);
    k_wcomb <<<DIM, 256, 0, stream>>>(Wz, Wi, bi, Wzi_bf, bzi);
    k_ebias <<<BN, 256, 0, stream>>>(lvl_emb, cam_emb, Wv, bv, ebias);
    k_mask  <<<(NQ+255)/256, 256, 0, stream>>>(bev, hitf, scalev, biasf);
    k_feat  <<<dim3(HW_/64, DIM/64, BN), 256, 0, stream>>>(features, featT);
    k_value_mfma<<<dim3(HW_/128, DIM/64, BN), 256, 0, stream>>>(featT, Wv_bf, ebias, value_bf);
    k_offattn<<<(MTOT/16 + 3)/4, 256, 0, stream>>>(queries, pos_emb, Woa_bf, bo, ba, off_ws, attw_ws);
    k_sample <<<NQ*32/256, 256, 0, stream>>>(value_bf, off_ws, attw_ws, ref3d, hitf, scalev, asum_bf);
    k_gemm_mfma<<<dim3((NQ+127)/128, DIM/64), 256, 0, stream>>>(asum_bf, Wzi_bf, bzi, biasf, bz, out, NQ);
}

// Round 8
// 361.189 us; speedup vs baseline: 1.7043x; 1.0306x over previous
//
#include <hip/hip_runtime.h>
#include <hip/hip_bf16.h>

#define BN     6
#define NQ     10000
#define DIM    256
#define HEADS  8
#define HDD    32
#define HF_    32
#define WF_    88
#define HW_    (HF_*WF_)     /* 2816 */
#define MTOT   (BN*NQ)       /* 60000 */
#define NTILES (MTOT/16)     /* 3750 */

typedef __attribute__((ext_vector_type(8))) unsigned short ushort8_t;
typedef __attribute__((ext_vector_type(8))) short bf16x8;
typedef __attribute__((ext_vector_type(4))) float f32x4;

static __device__ inline unsigned short f2bf(float x) {
    __hip_bfloat16 b = __float2bfloat16(x);
    return *(unsigned short*)&b;
}

// ---------------------------------------------------------------------------
// K_wcvt: f32 weights -> bf16 copies (Wv, [Wo;Wa]).
// ---------------------------------------------------------------------------
__global__ __launch_bounds__(256)
void k_wcvt(const float* __restrict__ Wv, const float* __restrict__ Wo,
            const float* __restrict__ Wa,
            unsigned short* __restrict__ Wv_bf, unsigned short* __restrict__ Woa_bf)
{
    const int i4 = (blockIdx.x*256 + threadIdx.x) * 4;
    if (i4 < 65536) {
        float4 v = *(const float4*)(Wv+i4);
        ushort4 p; p.x=f2bf(v.x);p.y=f2bf(v.y);p.z=f2bf(v.z);p.w=f2bf(v.w);
        *(ushort4*)(Wv_bf+i4) = p;
    }
    if (i4 < 32768) {
        float4 v = *(const float4*)(Wo+i4);
        ushort4 p; p.x=f2bf(v.x);p.y=f2bf(v.y);p.z=f2bf(v.z);p.w=f2bf(v.w);
        *(ushort4*)(Woa_bf+i4) = p;
    }
    if (i4 < 16384) {
        float4 v = *(const float4*)(Wa+i4);
        ushort4 p; p.x=f2bf(v.x);p.y=f2bf(v.y);p.z=f2bf(v.z);p.w=f2bf(v.w);
        *(ushort4*)(Woa_bf+32768+i4) = p;
    }
}

// ---------------------------------------------------------------------------
// K_wcomb: Wzi[j][k] = sum_t Wz[j][t]*Wi[t][k]  (bf16 out);
//          bzi[j]    = sum_t Wz[j][t]*bi[t].
// ---------------------------------------------------------------------------
__global__ __launch_bounds__(256)
void k_wcomb(const float* __restrict__ Wz, const float* __restrict__ Wi,
             const float* __restrict__ bi,
             unsigned short* __restrict__ Wzi_bf, float* __restrict__ bzi)
{
    const int j = blockIdx.x;
    const int k = threadIdx.x;
    __shared__ float wzr[DIM];
    wzr[k] = Wz[(size_t)j*DIM + k];
    __syncthreads();
    float s = 0.f;
    for (int t = 0; t < DIM; ++t) s += wzr[t] * Wi[(size_t)t*DIM + k];
    Wzi_bf[(size_t)j*DIM + k] = f2bf(s);
    if (k == 0) {
        float b = 0.f;
        for (int t = 0; t < DIM; ++t) b += wzr[t] * bi[t];
        bzi[j] = b;
    }
}

// ---------------------------------------------------------------------------
// K0: ebias[n][j] = sum_d (lvl[d]+cam[n][d]) * W_value[j][d] + b_value[j]
// ---------------------------------------------------------------------------
__global__ __launch_bounds__(256)
void k_ebias(const float* __restrict__ lvl, const float* __restrict__ cam,
             const float* __restrict__ Wv, const float* __restrict__ bv,
             float* __restrict__ ebias)
{
    const int n = blockIdx.x;
    const int j = threadIdx.x;
    __shared__ float e[DIM];
    e[j] = lvl[j] + cam[n*DIM + j];
    __syncthreads();
    const float* w = Wv + (size_t)j*DIM;
    float s = bv[j];
    for (int d = 0; d < DIM; ++d) s += e[d]*w[d];
    ebias[n*DIM + j] = s;
}

// ---------------------------------------------------------------------------
// K_mask: per-q hit flags, count scale, bias gate.
// ---------------------------------------------------------------------------
__global__ __launch_bounds__(256)
void k_mask(const int* __restrict__ bev, float* __restrict__ hitf,
            float* __restrict__ scale, float* __restrict__ biasf)
{
    const int q = blockIdx.x*256 + threadIdx.x;
    if (q >= NQ) return;
    float cnt = 0.f;
    #pragma unroll
    for (int n = 0; n < BN; ++n) {
        int hit = 0;
        #pragma unroll
        for (int z = 0; z < 4; ++z)
            hit |= (bev[(((size_t)n*NQ + q)*4 + z)*2] != 0);
        hitf[(size_t)n*NQ + q] = (float)hit;
        cnt += (float)hit;
    }
    biasf[q] = (cnt > 0.f) ? 1.f : 0.f;
    scale[q] = 1.f / fmaxf(cnt, 1.f);
}

// ---------------------------------------------------------------------------
// K_feat: transpose feat[cam][256 d][2816 p] f32 -> featT[cam][p][d] bf16.
// ---------------------------------------------------------------------------
__global__ __launch_bounds__(256)
void k_feat(const float* __restrict__ feat, unsigned short* __restrict__ featT)
{
    __shared__ float Tf[64][68];
    const int cam = blockIdx.z;
    const int d0 = blockIdx.y * 64;
    const int p0 = blockIdx.x * 64;
    const int tid = threadIdx.x;
    #pragma unroll
    for (int i = 0; i < 4; ++i) {
        const int d = (tid>>4) + i*16;
        const int p4 = (tid&15)*4;
        *(float4*)&Tf[d][p4] = *(const float4*)(feat + ((size_t)cam*DIM + d0 + d)*HW_ + p0 + p4);
    }
    __syncthreads();
    const int p = tid>>2, dq = tid&3;
    unsigned short* ob = featT + ((size_t)cam*HW_ + p0 + p)*DIM + d0;
    #pragma unroll
    for (int i = 0; i < 4; ++i) {
        const int d4 = dq*4 + i*16;
        ushort4 pk;
        pk.x = f2bf(Tf[d4+0][p]); pk.y = f2bf(Tf[d4+1][p]);
        pk.z = f2bf(Tf[d4+2][p]); pk.w = f2bf(Tf[d4+3][p]);
        *(ushort4*)(ob + d4) = pk;
    }
}

// ---------------------------------------------------------------------------
// K1: value GEMM via MFMA (LDS-tiled, 528 blocks).
// ---------------------------------------------------------------------------
__global__ __launch_bounds__(256)
void k_value_mfma(const unsigned short* __restrict__ featT,
                  const unsigned short* __restrict__ Wv_bf,
                  const float* __restrict__ ebias,
                  unsigned short* __restrict__ value_bf)
{
    __shared__ unsigned short Ap[128][72];
    __shared__ unsigned short Bc[64][72];
    const int cam = blockIdx.z;
    const int p0 = blockIdx.x * 128;
    const int c0 = blockIdx.y * 64;
    const int tid = threadIdx.x;
    const int lane = tid & 63, wave = tid >> 6;
    const int quad = lane >> 4, l15 = lane & 15;
    f32x4 acc[2][4] = {};
    const unsigned short* fbase = featT + ((size_t)cam*HW_ + p0)*DIM;

    for (int k0 = 0; k0 < DIM; k0 += 64) {
        #pragma unroll
        for (int i = 0; i < 4; ++i) {
            const int row = (tid>>3) + i*32;
            const int k8 = (tid&7)*8;
            *(ushort8_t*)&Ap[row][k8] = *(const ushort8_t*)(fbase + (size_t)row*DIM + k0 + k8);
        }
        #pragma unroll
        for (int i = 0; i < 2; ++i) {
            const int row = (tid>>3) + i*32;
            const int k8 = (tid&7)*8;
            *(ushort8_t*)&Bc[row][k8] = *(const ushort8_t*)(Wv_bf + (size_t)(c0+row)*DIM + k0 + k8);
        }
        __syncthreads();
        #pragma unroll
        for (int s = 0; s < 2; ++s) {
            const int kf = s*32 + quad*8;
            bf16x8 a[2], b[4];
            #pragma unroll
            for (int mt = 0; mt < 2; ++mt)
                a[mt] = *(const bf16x8*)&Ap[(wave*2+mt)*16 + l15][kf];
            #pragma unroll
            for (int nt = 0; nt < 4; ++nt)
                b[nt] = *(const bf16x8*)&Bc[nt*16 + l15][kf];
            #pragma unroll
            for (int mt = 0; mt < 2; ++mt)
                #pragma unroll
                for (int nt = 0; nt < 4; ++nt)
                    acc[mt][nt] = __builtin_amdgcn_mfma_f32_16x16x32_bf16(a[mt], b[nt], acc[mt][nt], 0,0,0);
        }
        __syncthreads();
    }
    #pragma unroll
    for (int nt = 0; nt < 4; ++nt) {
        const int c = c0 + nt*16 + l15;
        const float eb = ebias[cam*DIM + c];
        const int h = c >> 5, cc = c & 31;
        unsigned short* vb = value_bf + (size_t)(cam*HEADS + h)*HW_*HDD + cc;
        #pragma unroll
        for (int mt = 0; mt < 2; ++mt)
            #pragma unroll
            for (int r = 0; r < 4; ++r) {
                const int p = p0 + (wave*2+mt)*16 + quad*4 + r;
                vb[(size_t)p*HDD] = f2bf(acc[mt][nt][r] + eb);
            }
    }
}

// ---------------------------------------------------------------------------
// K2a: off/attn GEMM — persistent-B. 256 blocks x 512 threads, 1 block/CU.
// B (192x256 bf16) staged in LDS in two K=128 phases (50.7 KB each);
// 3 barriers total. Each wave streams ~2 independent 16-row m-tiles per
// phase: 16 HBM A-loads + 48 ds_read_b128+MFMA, no barriers in the loop.
// ---------------------------------------------------------------------------
__global__ __launch_bounds__(512)
void k_offattn(const float* __restrict__ Qr, const float* __restrict__ Pe,
               const unsigned short* __restrict__ Woa_bf,
               const float* __restrict__ boff, const float* __restrict__ battn,
               float* __restrict__ off_ws, float* __restrict__ attw_ws)
{
    __shared__ unsigned short Bw[192][132];   // pad 132: conflict-free-ish b128 reads
    const int tid  = threadIdx.x;
    const int wave = tid >> 6, lane = tid & 63;
    const int quad = lane >> 4, l15 = lane & 15;
    const int t0 = blockIdx.x*8 + wave;       // 2048 waves total
    const int t1 = t0 + 2048;

    f32x4 acc[2][12] = {};

    #pragma unroll
    for (int phase = 0; phase < 2; ++phase) {
        if (phase) __syncthreads();           // all waves done reading phase-0 B
        // ---- stage B[:, phase*128 .. +128): 3072 ushort8 units, 6/thread
        #pragma unroll
        for (int j = 0; j < 6; ++j) {
            const int u   = tid + j*512;
            const int row = u >> 4;           // 16 units per row
            const int c8  = (u & 15) * 8;
            *(ushort8_t*)&Bw[row][c8] =
                *(const ushort8_t*)(Woa_bf + (size_t)row*DIM + phase*128 + c8);
        }
        __syncthreads();

        #pragma unroll
        for (int ti = 0; ti < 2; ++ti) {
            const int tile = ti ? t1 : t0;
            if (tile >= NTILES) break;
            const int m0 = tile * 16;

            // A fragments for this K-half: row m0+l15, k = kc*32 + quad*8
            bf16x8 afr[4];
            const float* qrow = Qr + (size_t)(m0 + l15)*DIM + phase*128;
            const float* prow = Pe + (size_t)(m0 + l15)*DIM + phase*128;
            #pragma unroll
            for (int kc = 0; kc < 4; ++kc) {
                const int k = kc*32 + quad*8;
                const float4 x0 = *(const float4*)(qrow + k);
                const float4 x1 = *(const float4*)(qrow + k + 4);
                const float4 y0 = *(const float4*)(prow + k);
                const float4 y1 = *(const float4*)(prow + k + 4);
                ushort8_t u;
                u[0]=f2bf(x0.x+y0.x); u[1]=f2bf(x0.y+y0.y); u[2]=f2bf(x0.z+y0.z); u[3]=f2bf(x0.w+y0.w);
                u[4]=f2bf(x1.x+y1.x); u[5]=f2bf(x1.y+y1.y); u[6]=f2bf(x1.z+y1.z); u[7]=f2bf(x1.w+y1.w);
                afr[kc] = *(bf16x8*)&u;
            }
            #pragma unroll
            for (int kc = 0; kc < 4; ++kc) {
                const int kf = kc*32 + quad*8;
                #pragma unroll
                for (int nt = 0; nt < 12; ++nt) {
                    const bf16x8 b = *(const bf16x8*)&Bw[nt*16 + l15][kf];
                    acc[ti][nt] = __builtin_amdgcn_mfma_f32_16x16x32_bf16(afr[kc], b, acc[ti][nt], 0,0,0);
                }
            }
        }
    }

    // ---- epilogue: C layout col=l15, row=quad*4+r
    #pragma unroll
    for (int ti = 0; ti < 2; ++ti) {
        const int tile = ti ? t1 : t0;
        if (tile >= NTILES) break;
        const int m0 = tile * 16;
        #pragma unroll
        for (int nt = 0; nt < 12; ++nt) {
            const int col = nt*16 + l15;
            const float bias = (col < 128) ? boff[col] : battn[col-128];
            #pragma unroll
            for (int r = 0; r < 4; ++r) {
                const int m = m0 + quad*4 + r;
                const float v = acc[ti][nt][r] + bias;
                if (col < 128) off_ws [(size_t)m*128 + col]      = v;
                else           attw_ws[(size_t)m*64 + (col-128)] = v;
            }
        }
    }
}

// ---------------------------------------------------------------------------
// K2b: sampling fused with camera reduce — barrier-free (proven R5/R7 body).
// ---------------------------------------------------------------------------
__global__ __launch_bounds__(256)
void k_sample(const unsigned short* __restrict__ value_bf,
              const float* __restrict__ off_ws, const float* __restrict__ attw_ws,
              const float* __restrict__ ref3d, const float* __restrict__ hitf,
              const float* __restrict__ scale, unsigned short* __restrict__ asum_bf)
{
    const int gtid = blockIdx.x*256 + threadIdx.x;   // 320000 threads
    const int quarter = gtid & 3;
    const int h  = (gtid >> 2) & 7;
    const int q  = gtid >> 5;

    float acc[8];
    #pragma unroll
    for (int c = 0; c < 8; ++c) acc[c] = 0.f;

    #pragma unroll 1
    for (int n = 0; n < BN; ++n) {
        if (hitf[(size_t)n*NQ + q] == 0.f) continue;
        const size_t base = (size_t)n*NQ + q;

        const float4 a0 = *(const float4*)(attw_ws + base*64 + h*8);
        const float4 a1 = *(const float4*)(attw_ws + base*64 + h*8 + 4);
        float lg[8] = {a0.x,a0.y,a0.z,a0.w, a1.x,a1.y,a1.z,a1.w};
        float mx = -1e30f;
        #pragma unroll
        for (int p = 0; p < 8; ++p) mx = fmaxf(mx, lg[p]);
        float ssum = 0.f;
        #pragma unroll
        for (int p = 0; p < 8; ++p) { lg[p] = __expf(lg[p]-mx); ssum += lg[p]; }
        const float inv = 1.f/ssum;

        float off[16];
        #pragma unroll
        for (int i = 0; i < 4; ++i)
            *(float4*)&off[i*4] = *(const float4*)(off_ws + base*128 + h*16 + i*4);
        float ref[8];
        *(float4*)&ref[0] = *(const float4*)(ref3d + base*8);
        *(float4*)&ref[4] = *(const float4*)(ref3d + base*8 + 4);

        const unsigned short* vbase =
            value_bf + (size_t)(n*HEADS + h)*HW_*HDD + quarter*8;

        #pragma unroll
        for (int p = 0; p < 8; ++p) {
            const int z = p & 3;
            const float ax = ref[z*2+0]*WF_ + off[p*2+0] - 0.5f;
            const float ay = ref[z*2+1]*HF_ + off[p*2+1] - 0.5f;
            const float fx = floorf(ax), fy = floorf(ay);
            const float dx = ax-fx, dy = ay-fy;
            const int x0 = (int)fx, y0 = (int)fy;
            const float wp = lg[p]*inv;
            #pragma unroll
            for (int oy = 0; oy < 2; ++oy) {
                const int yi = y0 + oy;
                const float wy = oy ? dy : 1.f-dy;
                #pragma unroll
                for (int ox = 0; ox < 2; ++ox) {
                    const int xi = x0 + ox;
                    const float wx = ox ? dx : 1.f-dx;
                    const bool valid = ((unsigned)xi < WF_) & ((unsigned)yi < HF_);
                    const float cw = valid ? wp*wy*wx : 0.f;
                    const int xc = min(max(xi, 0), WF_-1);
                    const int yc = min(max(yi, 0), HF_-1);
                    const ushort8_t v = *(const ushort8_t*)(vbase + (size_t)(yc*WF_ + xc)*HDD);
                    #pragma unroll
                    for (int c = 0; c < 8; ++c)
                        acc[c] += cw * __uint_as_float(((unsigned)v[c]) << 16);
                }
            }
        }
    }

    const float sc = scale[q];
    ushort8_t o;
    #pragma unroll
    for (int c = 0; c < 8; ++c) o[c] = f2bf(acc[c]*sc);
    *(ushort8_t*)(asum_bf + (size_t)q*DIM + h*HDD + quarter*8) = o;
}

// ---------------------------------------------------------------------------
// K3: MFMA GEMM 128m x 64n: out = A_bf·Wzi^T + f(m)*bzi[j] + bz[j].
// ---------------------------------------------------------------------------
__global__ __launch_bounds__(256)
void k_gemm_mfma(const unsigned short* __restrict__ A_bf,
                 const unsigned short* __restrict__ W_bf,
                 const float* __restrict__ b1, const float* __restrict__ rowscale,
                 const float* __restrict__ b2,
                 float* __restrict__ out_f, int M)
{
    __shared__ unsigned short As[128][72];
    __shared__ unsigned short Bs[64][72];
    const int m0 = blockIdx.x * 128;
    const int j0 = blockIdx.y * 64;
    const int tid = threadIdx.x;
    const int lane = tid & 63, wave = tid >> 6;
    const int quad = lane >> 4, l15 = lane & 15;
    f32x4 acc[2][4] = {};

    for (int k0 = 0; k0 < DIM; k0 += 64) {
        #pragma unroll
        for (int i = 0; i < 4; ++i) {
            const int row = (tid>>3) + i*32;
            const int k8 = (tid&7)*8;
            ushort8_t v = {0,0,0,0,0,0,0,0};
            if (m0 + row < M)
                v = *(const ushort8_t*)(A_bf + (size_t)(m0+row)*DIM + k0 + k8);
            *(ushort8_t*)&As[row][k8] = v;
        }
        #pragma unroll
        for (int i = 0; i < 2; ++i) {
            const int row = (tid>>3) + i*32;
            const int k8 = (tid&7)*8;
            *(ushort8_t*)&Bs[row][k8] = *(const ushort8_t*)(W_bf + (size_t)(j0+row)*DIM + k0 + k8);
        }
        __syncthreads();
        #pragma unroll
        for (int s = 0; s < 2; ++s) {
            const int kf = s*32 + quad*8;
            bf16x8 a[2], b[4];
            #pragma unroll
            for (int mt = 0; mt < 2; ++mt)
                a[mt] = *(const bf16x8*)&As[(wave*2+mt)*16 + l15][kf];
            #pragma unroll
            for (int nt = 0; nt < 4; ++nt)
                b[nt] = *(const bf16x8*)&Bs[nt*16 + l15][kf];
            #pragma unroll
            for (int mt = 0; mt < 2; ++mt)
                #pragma unroll
                for (int nt = 0; nt < 4; ++nt)
                    acc[mt][nt] = __builtin_amdgcn_mfma_f32_16x16x32_bf16(a[mt], b[nt], acc[mt][nt], 0,0,0);
        }
        __syncthreads();
    }
    #pragma unroll
    for (int nt = 0; nt < 4; ++nt) {
        const int j = j0 + nt*16 + l15;
        const float b1j = b1[j], b2j = b2[j];
        #pragma unroll
        for (int mt = 0; mt < 2; ++mt) {
            #pragma unroll
            for (int r = 0; r < 4; ++r) {
                const int m = m0 + (wave*2+mt)*16 + quad*4 + r;
                if (m >= M) continue;
                out_f[(size_t)m*DIM + j] = acc[mt][nt][r] + rowscale[m]*b1j + b2j;
            }
        }
    }
}

// ---------------------------------------------------------------------------
extern "C" void kernel_launch(void* const* d_in, const int* in_sizes, int n_in,
                              void* d_out, int out_size, void* d_ws, size_t ws_size,
                              hipStream_t stream)
{
    const float* queries = (const float*)d_in[0];
    const float* pos_emb = (const float*)d_in[1];
    const float* lvl_emb = (const float*)d_in[2];
    const float* cam_emb = (const float*)d_in[3];
    const float* features= (const float*)d_in[4];
    const float* ref3d   = (const float*)d_in[5];
    const int*   bev     = (const int*)d_in[6];
    const float* Wv = (const float*)d_in[7];
    const float* bv = (const float*)d_in[8];
    const float* Wo = (const float*)d_in[9];
    const float* bo = (const float*)d_in[10];
    const float* Wa = (const float*)d_in[11];
    const float* ba = (const float*)d_in[12];
    const float* Wi = (const float*)d_in[13];
    const float* bi = (const float*)d_in[14];
    const float* Wz = (const float*)d_in[15];
    const float* bz = (const float*)d_in[16];
    float* out = (float*)d_out;

    char* ws = (char*)d_ws;
    size_t o = 0;
    auto alloc = [&](size_t bytes) { char* p = ws + o; o += (bytes + 255) & ~size_t(255); return p; };
    unsigned short* value_bf = (unsigned short*)alloc((size_t)BN*HEADS*HW_*HDD*2);
    unsigned short* featT    = (unsigned short*)alloc((size_t)BN*HW_*DIM*2);
    float* off_ws   = (float*)alloc((size_t)MTOT*128*4);
    float* attw_ws  = (float*)alloc((size_t)MTOT*64*4);
    unsigned short* asum_bf  = (unsigned short*)alloc((size_t)NQ*DIM*2);
    unsigned short* Wv_bf  = (unsigned short*)alloc(65536*2);
    unsigned short* Woa_bf = (unsigned short*)alloc(49152*2);
    unsigned short* Wzi_bf = (unsigned short*)alloc(65536*2);
    float* bzi    = (float*)alloc(DIM*4);
    float* hitf   = (float*)alloc((size_t)BN*NQ*4);
    float* scalev = (float*)alloc(NQ*4);
    float* biasf  = (float*)alloc(NQ*4);
    float* ebias  = (float*)alloc(BN*DIM*4);

    k_wcvt  <<<64, 256, 0, stream>>>(Wv, Wo, Wa, Wv_bf, Woa_bf);
    k_wcomb <<<DIM, 256, 0, stream>>>(Wz, Wi, bi, Wzi_bf, bzi);
    k_ebias <<<BN, 256, 0, stream>>>(lvl_emb, cam_emb, Wv, bv, ebias);
    k_mask  <<<(NQ+255)/256, 256, 0, stream>>>(bev, hitf, scalev, biasf);
    k_feat  <<<dim3(HW_/64, DIM/64, BN), 256, 0, stream>>>(features, featT);
    k_value_mfma<<<dim3(HW_/128, DIM/64, BN), 256, 0, stream>>>(featT, Wv_bf, ebias, value_bf);
    k_offattn<<<256, 512, 0, stream>>>(queries, pos_emb, Woa_bf, bo, ba, off_ws, attw_ws);
    k_sample <<<NQ*32/256, 256, 0, stream>>>(value_bf, off_ws, attw_ws, ref3d, hitf, scalev, asum_bf);
    k_gemm_mfma<<<dim3((NQ+127)/128, DIM/64), 256, 0, stream>>>(asum_bf, Wzi_bf, bzi, biasf, bz, out, NQ);
}